// Round 11
// baseline (306.672 us; speedup 1.0000x reference)
//
#include <hip/hip_runtime.h>
#include <cstdint>

typedef __attribute__((ext_vector_type(8))) short bf16x8;
typedef __attribute__((ext_vector_type(4))) float f32x4;

__device__ __forceinline__ unsigned short f2bf(float v) {
  unsigned u = __builtin_bit_cast(unsigned, v);
  u += 0x7FFFu + ((u >> 16) & 1u);   // RNE
  return (unsigned short)(u >> 16);
}

// async global->LDS, 16B per lane; LDS dest = wave-uniform base + lane*16
__device__ __forceinline__ void gload16(const unsigned short* g, unsigned short* l) {
  __builtin_amdgcn_global_load_lds(
      (const __attribute__((address_space(1))) void*)(uintptr_t)g,
      (__attribute__((address_space(3))) void*)(uint32_t)(uintptr_t)l,
      16, 0, 0);
}

// Templated single-pass bf16 NT GEMM core: C[128 x 64*NN*?] — block tile is
// 128 M x (NN*64) N with 2*NN waves; per-wave tile is ALWAYS 64x64 (acc[4][4],
// identical fragment/swizzle/staging math to the r0-verified 128^2 core; the
// NN=2 instantiation is bit-identical to it).
// NN=4 (512 thr): A is staged once per 256-wide N panel -> 25% less staged
// traffic for QKV/QK^T, attacking the measured ~11 TB/s staging-supply bound.
// Resources at NN=4: LDS 48 KiB -> 2 blocks/CU; regs ~120 -> needs cap >=128,
// so __launch_bounds__(512,4) (r7 lesson: cap < acc+locals => scratch spill).
// LDS tiles: A 128 x 64, B (NN*64) x 64 shorts; XOR swizzle: row r's logical
// 16B chunk c at physical c^(r&7) -> conflict-free ds_read_b128.
template<int NN>
__device__ __forceinline__ void gemm_core(
    const unsigned short* __restrict__ A, const unsigned short* __restrict__ B,
    int lda, int ldb, int K,
    unsigned short* ldsA, unsigned short* ldsB, f32x4 acc[4][4])
{
  constexpr int AROWS = 64 / NN;                  // A rows staged per wave
  const int tid  = threadIdx.x;
  const int wave = tid >> 6;
  const int lane = tid & 63;
  const int wr = wave / NN;                       // 0..1   (M)
  const int wc = wave % NN;                       // 0..NN-1 (N)
  const int lrow = lane & 15;
  const int kq = lane >> 4;

  // staging: lane covers row base+sr, swizzled chunk (lane&7)^(sr&7)
  const int sr = lane >> 3;                       // 0..7
  const int sc = (lane & 7) ^ (sr & 7);           // swizzled source chunk
  const unsigned short* ga = A + (long)(wave * AROWS + sr) * lda + sc * 8;
  const unsigned short* gb = B + (long)(wave * 32 + sr) * ldb + sc * 8;
  unsigned short* lA = ldsA + wave * AROWS * 64;
  unsigned short* lB = ldsB + wave * 2048;        // 32 rows per wave

  const int pc0 = ((0 * 4 + kq) ^ (lrow & 7)) * 8;   // k-step 0 read chunk
  const int pc1 = ((1 * 4 + kq) ^ (lrow & 7)) * 8;   // k-step 1 read chunk

#pragma unroll 1
  for (int kb = 0; kb < K; kb += 64) {
    __syncthreads();  // previous tile fully consumed
#pragma unroll
    for (int i = 0; i < AROWS / 8; ++i)
      gload16(ga + kb + (long)i * 8 * lda, lA + i * 512);
#pragma unroll
    for (int i = 0; i < 4; ++i)
      gload16(gb + kb + (long)i * 8 * ldb, lB + i * 512);
    __syncthreads();  // drains vmcnt -> LDS valid

    bf16x8 af[4], bfr[4];
    // k-step 0 (k = kb .. kb+31)
#pragma unroll
    for (int i = 0; i < 4; ++i)
      af[i] = *(const bf16x8*)(ldsA + (wr * 64 + i * 16 + lrow) * 64 + pc0);
#pragma unroll
    for (int j = 0; j < 4; ++j)
      bfr[j] = *(const bf16x8*)(ldsB + (wc * 64 + j * 16 + lrow) * 64 + pc0);
#pragma unroll
    for (int i = 0; i < 4; ++i)
#pragma unroll
      for (int j = 0; j < 4; ++j)
        acc[i][j] = __builtin_amdgcn_mfma_f32_16x16x32_bf16(af[i], bfr[j], acc[i][j], 0, 0, 0);

    // k-step 1 (k = kb+32 .. kb+63)
#pragma unroll
    for (int i = 0; i < 4; ++i)
      af[i] = *(const bf16x8*)(ldsA + (wr * 64 + i * 16 + lrow) * 64 + pc1);
#pragma unroll
    for (int j = 0; j < 4; ++j)
      bfr[j] = *(const bf16x8*)(ldsB + (wc * 64 + j * 16 + lrow) * 64 + pc1);
#pragma unroll
    for (int i = 0; i < 4; ++i)
#pragma unroll
      for (int j = 0; j < 4; ++j)
        acc[i][j] = __builtin_amdgcn_mfma_f32_16x16x32_bf16(af[i], bfr[j], acc[i][j], 0, 0, 0);
  }
}

// QKV projection: x[8192,1024] * W[1024,1024]^T + b, fused over Q/K/V.
// 128 M x 256 N tile, 8 waves. blockIdx.y = sel*4 + nb (nb = 256-wide block).
// Q,K stored row-major bf16; V stored transposed per batch: Vt[b][d][m].
__global__ __launch_bounds__(512, 4) void gemm_qkv(
    const unsigned short* __restrict__ xh,
    const unsigned short* __restrict__ wh,
    const float* __restrict__ bq, const float* __restrict__ bk, const float* __restrict__ bv,
    unsigned short* __restrict__ Qh, unsigned short* __restrict__ Kh,
    unsigned short* __restrict__ Vth)
{
  __shared__ __align__(16) unsigned short ldsA[8192];    // 128 x 64
  __shared__ __align__(16) unsigned short ldsB[16384];   // 256 x 64
  const int Mblk = blockIdx.x * 128;
  const int sel  = blockIdx.y >> 2;   // 0=Q 1=K 2=V
  const int nb   = blockIdx.y & 3;    // 256-wide col block within 1024

  const unsigned short* A = xh + (long)Mblk * 1024;
  const unsigned short* B = wh + sel * 1048576 + (long)(nb * 256) * 1024;
  const float* bias = (sel == 0) ? bq : (sel == 1) ? bk : bv;

  f32x4 acc[4][4] = {};
  gemm_core<4>(A, B, 1024, 1024, 1024, ldsA, ldsB, acc);

  const int lane = threadIdx.x & 63, wave = threadIdx.x >> 6;
  const int wr = wave >> 2, wc = wave & 3;
  const int lrow = lane & 15, kq = lane >> 4;

#pragma unroll
  for (int i = 0; i < 4; ++i) {
#pragma unroll
    for (int j = 0; j < 4; ++j) {
      const int col = nb * 256 + wc * 64 + j * 16 + lrow;   // output feature d
      const float bsv = bias[col];
#pragma unroll
      for (int r = 0; r < 4; ++r) {
        const int tok = Mblk + wr * 64 + i * 16 + kq * 4 + r;  // token index
        const unsigned short h = f2bf(acc[i][j][r] + bsv);
        if (sel == 2) {
          Vth[(long)(tok >> 11) * 2097152 + (long)col * 2048 + (tok & 2047)] = h;
        } else if (sel == 0) {
          Qh[(long)tok * 1024 + col] = h;
        } else {
          Kh[(long)tok * 1024 + col] = h;
        }
      }
    }
  }
}

// Batched NT GEMM, fp32 out, 128x256 tile (8 waves): C[z] = alpha*A[z]*B[z]^T
__global__ __launch_bounds__(512, 4) void gemm_f32out_w(
    const unsigned short* __restrict__ A, const unsigned short* __restrict__ B,
    int lda, int ldb, int K,
    long sA, long sB, float* __restrict__ C, int ldc, long sC, float alpha)
{
  __shared__ __align__(16) unsigned short ldsA[8192];
  __shared__ __align__(16) unsigned short ldsB[16384];
  const int Mblk = blockIdx.x * 128;
  const int Nblk = blockIdx.y * 256;
  const long z = blockIdx.z;
  const unsigned short* Ab = A + z * sA + (long)Mblk * lda;
  const unsigned short* Bb = B + z * sB + (long)Nblk * ldb;
  float* Cb = C + z * sC;

  f32x4 acc[4][4] = {};
  gemm_core<4>(Ab, Bb, lda, ldb, K, ldsA, ldsB, acc);

  const int lane = threadIdx.x & 63, wave = threadIdx.x >> 6;
  const int wr = wave >> 2, wc = wave & 3;
  const int lrow = lane & 15, kq = lane >> 4;
#pragma unroll
  for (int i = 0; i < 4; ++i)
#pragma unroll
    for (int j = 0; j < 4; ++j)
#pragma unroll
      for (int r = 0; r < 4; ++r) {
        const int row = Mblk + wr * 64 + i * 16 + kq * 4 + r;
        const int col = Nblk + wc * 64 + j * 16 + lrow;
        Cb[(long)row * ldc + col] = alpha * acc[i][j][r];
      }
}

// Batched NT GEMM, fp32 out, 128x128 tile (4 waves) — r0-verified shape (PV).
__global__ __launch_bounds__(256, 4) void gemm_f32out(
    const unsigned short* __restrict__ A, const unsigned short* __restrict__ B,
    int lda, int ldb, int K,
    long sA, long sB, float* __restrict__ C, int ldc, long sC, float alpha)
{
  __shared__ __align__(16) unsigned short ldsA[8192];
  __shared__ __align__(16) unsigned short ldsB[8192];
  const int Mblk = blockIdx.x * 128;
  const int Nblk = blockIdx.y * 128;
  const long z = blockIdx.z;
  const unsigned short* Ab = A + z * sA + (long)Mblk * lda;
  const unsigned short* Bb = B + z * sB + (long)Nblk * ldb;
  float* Cb = C + z * sC;

  f32x4 acc[4][4] = {};
  gemm_core<2>(Ab, Bb, lda, ldb, K, ldsA, ldsB, acc);

  const int lane = threadIdx.x & 63, wave = threadIdx.x >> 6;
  const int wr = wave >> 1, wc = wave & 1;
  const int lrow = lane & 15, kq = lane >> 4;
#pragma unroll
  for (int i = 0; i < 4; ++i)
#pragma unroll
    for (int j = 0; j < 4; ++j)
#pragma unroll
      for (int r = 0; r < 4; ++r) {
        const int row = Mblk + wr * 64 + i * 16 + kq * 4 + r;
        const int col = Nblk + wc * 64 + j * 16 + lrow;
        Cb[(long)row * ldc + col] = alpha * acc[i][j][r];
      }
}

// Row softmax over 2048 entries, in place (fp32) + bf16 copy for the PV GEMM.
// One wave per row: no LDS, no barriers; 6-step __shfl_xor reductions.
__global__ __launch_bounds__(256) void softmax_rows(
    float* __restrict__ S, unsigned short* __restrict__ Ph)
{
  const int wave = threadIdx.x >> 6;
  const int lane = threadIdx.x & 63;
  const long row = (long)blockIdx.x * 4 + wave;
  float* rp = S + row * 2048;
  f32x4* rv = reinterpret_cast<f32x4*>(rp);

  f32x4 x[8];
#pragma unroll
  for (int k = 0; k < 8; ++k) x[k] = rv[lane + 64 * k];

  float m = x[0][0];
#pragma unroll
  for (int k = 0; k < 8; ++k)
#pragma unroll
    for (int e = 0; e < 4; ++e) m = fmaxf(m, x[k][e]);
  for (int o = 32; o; o >>= 1) m = fmaxf(m, __shfl_xor(m, o, 64));

  float s = 0.f;
#pragma unroll
  for (int k = 0; k < 8; ++k)
#pragma unroll
    for (int e = 0; e < 4; ++e) { x[k][e] = __expf(x[k][e] - m); s += x[k][e]; }
  for (int o = 32; o; o >>= 1) s += __shfl_xor(s, o, 64);
  const float inv = 1.0f / s;

  const long pb = row * 2048;
#pragma unroll
  for (int k = 0; k < 8; ++k) {
    x[k] *= inv;
    rv[lane + 64 * k] = x[k];
    ushort4 p;
    p.x = f2bf(x[k][0]); p.y = f2bf(x[k][1]);
    p.z = f2bf(x[k][2]); p.w = f2bf(x[k][3]);
    *reinterpret_cast<ushort4*>(Ph + pb + (lane + 64 * k) * 4) = p;
  }
}

// One fused cast pass: x (2,097,152 float4) then Wq|Wk|Wv (262,144 float4 each).
__global__ __launch_bounds__(256) void to_bf16_all(
    const float* __restrict__ x,
    const float* __restrict__ Wq, const float* __restrict__ Wk,
    const float* __restrict__ Wv,
    unsigned short* __restrict__ xh, unsigned short* __restrict__ wh)
{
  const int stride = gridDim.x * 256;
  for (int i = blockIdx.x * 256 + threadIdx.x; i < 2883584; i += stride) {
    const float* src; unsigned short* dst; int off;
    if (i < 2097152)      { src = x;  dst = xh; off = i; }
    else {
      const int j = i - 2097152;
      const int sel = j >> 18;          // 0..2 (262144 float4 per W)
      off = j & 262143;
      src = (sel == 0) ? Wq : (sel == 1) ? Wk : Wv;
      dst = wh + (long)sel * 1048576;
    }
    const float4 v = reinterpret_cast<const float4*>(src)[off];
    ushort4 h;
    h.x = f2bf(v.x); h.y = f2bf(v.y); h.z = f2bf(v.z); h.w = f2bf(v.w);
    reinterpret_cast<ushort4*>(dst)[off] = h;
  }
}

extern "C" void kernel_launch(void* const* d_in, const int* in_sizes, int n_in,
                              void* d_out, int out_size, void* d_ws, size_t ws_size,
                              hipStream_t stream)
{
  const float* x  = (const float*)d_in[0];
  const float* Wq = (const float*)d_in[1];
  const float* bq = (const float*)d_in[2];
  const float* Wk = (const float*)d_in[3];
  const float* bk = (const float*)d_in[4];
  const float* Wv = (const float*)d_in[5];
  const float* bv = (const float*)d_in[6];

  float* out  = (float*)d_out;                 // [4,2048,1024]
  float* attn = (float*)d_out + 8388608;       // [4,2048,2048]

  unsigned short* ws  = (unsigned short*)d_ws;
  unsigned short* xh  = ws;                    //  8,388,608
  unsigned short* wh  = xh + 8388608;          //  3,145,728 (Wq|Wk|Wv)
  unsigned short* Qh  = wh + 3145728;          //  8,388,608
  unsigned short* Kh  = Qh + 8388608;          //  8,388,608
  unsigned short* Vth = Kh + 8388608;          //  8,388,608  Vt[b][d][m]
  unsigned short* Ph  = Vth + 8388608;         // 16,777,216  P bf16

  to_bf16_all<<<2048, 256, 0, stream>>>(x, Wq, Wk, Wv, xh, wh);

  // Q,K,V projections (M=8192, N=3x1024, K=1024), 128x256 tiles: 768 blocks
  gemm_qkv<<<dim3(64, 12), 512, 0, stream>>>(xh, wh, bq, bk, bv, Qh, Kh, Vth);

  // scores = Q K^T / 32 -> fp32, 128x256 tiles: 512 blocks
  gemm_f32out_w<<<dim3(16, 8, 4), 512, 0, stream>>>(Qh, Kh, 1024, 1024, 1024,
      2097152L, 2097152L, attn, 2048, 4194304L, 0.03125f);

  // softmax rows in place + emit P bf16 (one wave per row)
  softmax_rows<<<2048, 256, 0, stream>>>(attn, Ph);

  // out = P * Vt^T, 128x128 tiles (r0-verified shape)
  gemm_f32out<<<dim3(16, 8, 4), 256, 0, stream>>>(Ph, Vth, 2048, 2048, 2048,
      4194304L, 2097152L, out, 1024, 2097152L, 1.0f);
}